// Round 11
// baseline (468.562 us; speedup 1.0000x reference)
//
#include <hip/hip_runtime.h>
#include <hip/hip_cooperative_groups.h>

namespace cg = cooperative_groups;

// Problem: B=2, S=2048, D=1024, H=16, hd=64. fp32 in/out; internal bf16 MFMA.
#define S_LEN 2048
#define DIM   1024
#define NHEAD 16
#define HDIM  64
#define Q_PRESCALE 0.045084220027780106f   // log2(e)/sqrt(D): exp2 softmax

typedef __attribute__((ext_vector_type(8))) short  short8;   // 8 bf16
typedef __attribute__((ext_vector_type(4))) float  floatx4;  // MFMA C/D
typedef __attribute__((ext_vector_type(4))) unsigned short ushort4v;

__device__ inline unsigned short f2bf(float f) {
  unsigned v = __builtin_bit_cast(unsigned, f);
  v += 0x7FFFu + ((v >> 16) & 1u);   // RTNE
  return (unsigned short)(v >> 16);
}

// async global->LDS, 16B/lane; LDS dest = wave-uniform base + lane*16.
__device__ inline void async16(const unsigned short* g, unsigned short* l) {
  __builtin_amdgcn_global_load_lds(
      (const __attribute__((address_space(1))) unsigned int*)g,
      (__attribute__((address_space(3))) unsigned int*)l, 16, 0, 0);
}

// ==================== fused cooperative kernel ====================
// 256 blocks x 512 threads (8 waves). LDS 52 KB static -> 1+ block/CU guaranteed.
__global__ __launch_bounds__(512, 2) void fused_kernel(
    const float* __restrict__ X, const float* __restrict__ Wqkv,
    const float* __restrict__ bqkv, const float* __restrict__ Wout,
    const float* __restrict__ bout, float* __restrict__ outp,
    unsigned short* __restrict__ Wqkvt, unsigned short* __restrict__ Woutt,
    unsigned short* __restrict__ attnB, unsigned short* __restrict__ Qg,
    unsigned short* __restrict__ Kg, unsigned short* __restrict__ Vgt,
    unsigned short* __restrict__ Xb) {
  cg::grid_group grid = cg::this_grid();
  __shared__ __align__(16) unsigned char smem[53248];
  const int T = threadIdx.x;
  const int bId = blockIdx.x;
  const int lane = T & 63, wave = T >> 6;        // wave 0..7
  const int quad = lane >> 4, l16 = lane & 15;
  const int lr = lane >> 3, lc = lane & 7;
  const int sc8v = (lc ^ lr) * 8;                // staging chunk swizzle
  const int sw = l16 & 7;
  const int p0 = (quad ^ sw) * 8, p1 = ((4 + quad) ^ sw) * 8;   // frag reads

  //---------- phase 1: X fp32->bf16; Wqkv/Wout transpose+convert ----------
  {
    for (size_t i = ((size_t)bId * 512 + T) * 8; i < (size_t)4194304;
         i += (size_t)256 * 512 * 8) {
      float4 a = *(const float4*)&X[i];
      float4 b = *(const float4*)&X[i + 4];
      short8 o;
      o[0] = (short)f2bf(a.x); o[1] = (short)f2bf(a.y);
      o[2] = (short)f2bf(a.z); o[3] = (short)f2bf(a.w);
      o[4] = (short)f2bf(b.x); o[5] = (short)f2bf(b.y);
      o[6] = (short)f2bf(b.z); o[7] = (short)f2bf(b.w);
      *(short8*)&Xb[i] = o;
    }
    const int sub = T >> 8, tid = T & 255;
    unsigned short (*tile)[33] = (unsigned short (*)[33])(smem + sub * 2112);
    const int tx = tid & 31, ty = tid >> 5;      // 32 x 8
    for (int ti = bId * 2 + sub; ti < 4096; ti += 512) {   // uniform 8 iters/sub
      const float* in; unsigned short* out; int N, tn, tk;
      if (ti < 3072) { in = Wqkv; out = Wqkvt; N = 3072; tn = ti % 96; tk = ti / 96; }
      else { int u = ti - 3072; in = Wout; out = Woutt; N = 1024; tn = u & 31; tk = u >> 5; }
      int n0 = tn * 32, k0 = tk * 32;
#pragma unroll
      for (int i = 0; i < 32; i += 8)
        tile[ty + i][tx] = f2bf(in[(size_t)(k0 + ty + i) * N + n0 + tx]);
      __syncthreads();
#pragma unroll
      for (int i = 0; i < 32; i += 8)
        out[(size_t)(n0 + ty + i) * 1024 + k0 + tx] = tile[tx][ty + i];
      __syncthreads();
    }
  }
  __threadfence();
  grid.sync();

  //---------- phase 2: qkv GEMM, 128x128 tiles, exactly 3 per block ----------
  {
    unsigned short (*As)[64] = (unsigned short (*)[64])smem;            // 16 KB
    unsigned short (*Bs)[64] = (unsigned short (*)[64])(smem + 16384);  // 16 KB
    const int wm = (wave & 3) * 32, wn = (wave >> 2) * 64;
    for (int j = 0; j < 3; j++) {
      const int ti = bId * 3 + j;                 // 768 tiles
      const int m0 = (ti / 24) * 128, n0 = (ti % 24) * 128;
      floatx4 acc[2][4];
#pragma unroll
      for (int mi = 0; mi < 2; mi++)
#pragma unroll
        for (int ni = 0; ni < 4; ni++) acc[mi][ni] = (floatx4){0.f, 0.f, 0.f, 0.f};
      for (int k0 = 0; k0 < DIM; k0 += 64) {
        const int rb = wave * 16;
        async16(&Xb[(size_t)(m0 + rb + lr) * DIM + k0 + sc8v], &As[rb][0]);
        async16(&Xb[(size_t)(m0 + rb + 8 + lr) * DIM + k0 + sc8v], &As[rb + 8][0]);
        async16(&Wqkvt[(size_t)(n0 + rb + lr) * DIM + k0 + sc8v], &Bs[rb][0]);
        async16(&Wqkvt[(size_t)(n0 + rb + 8 + lr) * DIM + k0 + sc8v], &Bs[rb + 8][0]);
        __syncthreads();
        short8 a0[2], a1[2];
#pragma unroll
        for (int mi = 0; mi < 2; mi++) {
          int row = wm + mi * 16 + l16;
          a0[mi] = *(const short8*)&As[row][p0];
          a1[mi] = *(const short8*)&As[row][p1];
        }
#pragma unroll
        for (int ni = 0; ni < 4; ni++) {
          int row = wn + ni * 16 + l16;
          short8 b0 = *(const short8*)&Bs[row][p0];
          short8 b1 = *(const short8*)&Bs[row][p1];
#pragma unroll
          for (int mi = 0; mi < 2; mi++) {
            acc[mi][ni] = __builtin_amdgcn_mfma_f32_16x16x32_bf16(a0[mi], b0, acc[mi][ni], 0, 0, 0);
            acc[mi][ni] = __builtin_amdgcn_mfma_f32_16x16x32_bf16(a1[mi], b1, acc[mi][ni], 0, 0, 0);
          }
        }
        __syncthreads();
      }
      // epilogue scatter: section (q/k/v) and head per wave-column
      const int section = n0 >> 10;
      const int head = ((n0 + wn) >> 6) & 15;
#pragma unroll
      for (int mi = 0; mi < 2; mi++) {
        int mg = m0 + wm + mi * 16 + quad * 4;
        int bb = mg >> 11, sb = mg & 2047;
        size_t y = (size_t)bb * NHEAD + head;
        if (section == 2) {
#pragma unroll
          for (int ni = 0; ni < 4; ni++) {
            int hdi = ni * 16 + l16;
            float bv = bqkv[n0 + wn + hdi];
            ushort4v o;
#pragma unroll
            for (int r = 0; r < 4; r++) o[r] = f2bf(acc[mi][ni][r] + bv);
            *(ushort4v*)&Vgt[(y * HDIM + hdi) * S_LEN + sb] = o;
          }
        } else if (section == 0) {
#pragma unroll
          for (int ni = 0; ni < 4; ni++) {
            int hdi = ni * 16 + l16;
            float bv = bqkv[n0 + wn + hdi];
#pragma unroll
            for (int r = 0; r < 4; r++)
              Qg[(y * S_LEN + sb + r) * HDIM + hdi] = f2bf((acc[mi][ni][r] + bv) * Q_PRESCALE);
          }
        } else {
#pragma unroll
          for (int ni = 0; ni < 4; ni++) {
            int hdi = ni * 16 + l16;
            float bv = bqkv[n0 + wn + hdi];
#pragma unroll
            for (int r = 0; r < 4; r++)
              Kg[(y * S_LEN + sb + r) * HDIM + hdi] = f2bf(acc[mi][ni][r] + bv);
          }
        }
      }
    }
  }
  __threadfence();
  grid.sync();

  //---------- phase 3: attention, 128-row q-tiles, static pair per block ----------
  // block = (y, ii): q-tiles qb=ii then 15-ii; 34 uniform barrier-steps.
  {
    unsigned short (*Ks)[64][64] = (unsigned short (*)[64][64])smem;             // 16 KB
    unsigned short (*Vs)[64][64] = (unsigned short (*)[64][64])(smem + 16384);   // 16 KB
    unsigned short (*Ones)[64]   = (unsigned short (*)[64])(smem + 32768);       // 2 KB
    unsigned short (*Ps)[16][72] = (unsigned short (*)[16][72])(smem + 34816);   // 18 KB
    const int y = bId >> 3, ii = bId & 7;
    const int b = y >> 4, h = y & 15;
    const unsigned short* Qh = Qg + (size_t)y * S_LEN * HDIM;
    const unsigned short* Kh = Kg + (size_t)y * S_LEN * HDIM;
    const unsigned short* Vh = Vgt + (size_t)y * HDIM * S_LEN;

    if (T < 128) {   // Ones rows (row0 = 1.0): swizzle-invariant constants
      int row = T >> 3, c = (T & 7) * 8;
      unsigned short vv = (row == 0) ? (unsigned short)0x3F80 : (unsigned short)0;
      short8 o;
#pragma unroll
      for (int jj = 0; jj < 8; jj++) o[jj] = (short)vv;
      *(short8*)&Ones[row][c] = o;
    }

    const int nT1 = 2 * ii + 2;
    short8 aq0, aq1;
    floatx4 o_acc[5];
    {   // stage step 0 (qb=ii, j0=0) -> buf0: wave stages 8 K-rows + 8 V-rows
      const int rb = wave * 8;
      async16(&Kh[(size_t)(rb + lr) * HDIM + sc8v], &Ks[0][rb][0]);
      async16(&Vh[(size_t)(rb + lr) * S_LEN + sc8v], &Vs[0][rb][0]);
    }
    for (int s = 0; s < 34; s++) {
      const bool first = (s < nT1);
      const int qb = first ? ii : 15 - ii;
      const int tt = first ? s : s - nT1;
      const int q0 = qb * 128, j0 = tt * 64;
      if (tt == 0) {   // new q-tile: Q frags + acc reset
        const unsigned short* qp = &Qh[(size_t)(q0 + wave * 16 + l16) * HDIM];
        aq0 = *(const short8*)&qp[quad * 8];
        aq1 = *(const short8*)&qp[32 + quad * 8];
#pragma unroll
        for (int dt = 0; dt < 5; dt++) o_acc[dt] = (floatx4){0.f, 0.f, 0.f, 0.f};
      }
      const int buf = s & 1;
      __syncthreads();                  // drain async stage of `buf` (+Ones @ s=0)
      if (s + 1 < 34) {                 // prefetch next step's tile
        const int tt2 = (s + 1 < nT1) ? s + 1 : s + 1 - nT1;
        const int j1 = tt2 * 64, nb = 1 - buf;
        const int rb = wave * 8;
        async16(&Kh[(size_t)(j1 + rb + lr) * HDIM + sc8v], &Ks[nb][rb][0]);
        async16(&Vh[(size_t)(rb + lr) * S_LEN + j1 + sc8v], &Vs[nb][rb][0]);
      }
      const int W0 = q0 + wave * 16;    // wave's first q-row
      if (j0 <= W0 + 15) {              // skip fully-masked waves (barrier stays uniform)
        floatx4 sc[4];
#pragma unroll
        for (int nt = 0; nt < 4; nt++) {
          short8 kb0 = *(const short8*)&Ks[buf][nt * 16 + l16][p0];
          short8 kb1 = *(const short8*)&Ks[buf][nt * 16 + l16][p1];
          sc[nt] = (floatx4){0.f, 0.f, 0.f, 0.f};
          sc[nt] = __builtin_amdgcn_mfma_f32_16x16x32_bf16(aq0, kb0, sc[nt], 0, 0, 0);
          sc[nt] = __builtin_amdgcn_mfma_f32_16x16x32_bf16(aq1, kb1, sc[nt], 0, 0, 0);
        }
        if (j0 + 63 <= W0) {            // fully unmasked
#pragma unroll
          for (int nt = 0; nt < 4; nt++)
#pragma unroll
            for (int r = 0; r < 4; r++)
              Ps[wave][quad * 4 + r][nt * 16 + l16] = f2bf(exp2f(sc[nt][r]));
        } else {                        // diagonal: partial mask
#pragma unroll
          for (int nt = 0; nt < 4; nt++) {
            int keyg = j0 + nt * 16 + l16;
#pragma unroll
            for (int r = 0; r < 4; r++) {
              int qg = W0 + quad * 4 + r;
              float p = exp2f(sc[nt][r]);
              p = (keyg <= qg) ? p : 0.f;
              Ps[wave][quad * 4 + r][nt * 16 + l16] = f2bf(p);
            }
          }
        }
        // same-wave LDS RAW: compiler inserts lgkmcnt wait
        short8 ap0 = *(const short8*)&Ps[wave][l16][quad * 8];
        short8 ap1 = *(const short8*)&Ps[wave][l16][32 + quad * 8];
#pragma unroll
        for (int dt = 0; dt < 5; dt++) {
          short8 vb0 = (dt < 4) ? *(const short8*)&Vs[buf][dt * 16 + l16][p0]
                                : *(const short8*)&Ones[l16][p0];
          short8 vb1 = (dt < 4) ? *(const short8*)&Vs[buf][dt * 16 + l16][p1]
                                : *(const short8*)&Ones[l16][p1];
          o_acc[dt] = __builtin_amdgcn_mfma_f32_16x16x32_bf16(ap0, vb0, o_acc[dt], 0, 0, 0);
          o_acc[dt] = __builtin_amdgcn_mfma_f32_16x16x32_bf16(ap1, vb1, o_acc[dt], 0, 0, 0);
        }
      }
      if (tt == 2 * qb + 1) {           // last tile of this q-block: write O
        float linv[4];
#pragma unroll
        for (int r = 0; r < 4; r++)
          linv[r] = 1.0f / __shfl(o_acc[4][r], quad << 4);
#pragma unroll
        for (int dt = 0; dt < 4; dt++)
#pragma unroll
          for (int r = 0; r < 4; r++) {
            int qg = q0 + wave * 16 + quad * 4 + r;
            attnB[(size_t)(b * S_LEN + qg) * DIM + h * HDIM + dt * 16 + l16] =
                f2bf(o_acc[dt][r] * linv[r]);
          }
      }
    }
  }
  __threadfence();
  grid.sync();

  //---------- phase 4: out GEMM, 128x128, exactly 1 tile per block ----------
  {
    unsigned short (*As)[64] = (unsigned short (*)[64])smem;
    unsigned short (*Bs)[64] = (unsigned short (*)[64])(smem + 16384);
    const int wm = (wave & 3) * 32, wn = (wave >> 2) * 64;
    const int m0 = (bId >> 3) * 128, n0 = (bId & 7) * 128;
    floatx4 acc[2][4];
#pragma unroll
    for (int mi = 0; mi < 2; mi++)
#pragma unroll
      for (int ni = 0; ni < 4; ni++) acc[mi][ni] = (floatx4){0.f, 0.f, 0.f, 0.f};
    for (int k0 = 0; k0 < DIM; k0 += 64) {
      const int rb = wave * 16;
      async16(&attnB[(size_t)(m0 + rb + lr) * DIM + k0 + sc8v], &As[rb][0]);
      async16(&attnB[(size_t)(m0 + rb + 8 + lr) * DIM + k0 + sc8v], &As[rb + 8][0]);
      async16(&Woutt[(size_t)(n0 + rb + lr) * DIM + k0 + sc8v], &Bs[rb][0]);
      async16(&Woutt[(size_t)(n0 + rb + 8 + lr) * DIM + k0 + sc8v], &Bs[rb + 8][0]);
      __syncthreads();
      short8 a0[2], a1[2];
#pragma unroll
      for (int mi = 0; mi < 2; mi++) {
        int row = wm + mi * 16 + l16;
        a0[mi] = *(const short8*)&As[row][p0];
        a1[mi] = *(const short8*)&As[row][p1];
      }
#pragma unroll
      for (int ni = 0; ni < 4; ni++) {
        int row = wn + ni * 16 + l16;
        short8 b0 = *(const short8*)&Bs[row][p0];
        short8 b1 = *(const short8*)&Bs[row][p1];
#pragma unroll
        for (int mi = 0; mi < 2; mi++) {
          acc[mi][ni] = __builtin_amdgcn_mfma_f32_16x16x32_bf16(a0[mi], b0, acc[mi][ni], 0, 0, 0);
          acc[mi][ni] = __builtin_amdgcn_mfma_f32_16x16x32_bf16(a1[mi], b1, acc[mi][ni], 0, 0, 0);
        }
      }
      __syncthreads();
    }
#pragma unroll
    for (int ni = 0; ni < 4; ni++) {
      int n = n0 + wn + ni * 16 + l16;
      float bv = bout[n];
#pragma unroll
      for (int mi = 0; mi < 2; mi++) {
        int mg = m0 + wm + mi * 16 + quad * 4;
#pragma unroll
        for (int r = 0; r < 4; r++)
          outp[(size_t)(mg + r) * DIM + n] = acc[mi][ni][r] + bv;
      }
    }
  }
}

// ==================== fallback: round-10 multi-kernel path ====================
__global__ __launch_bounds__(256) void cvt_kernel(
    const float* __restrict__ in, unsigned short* __restrict__ out, int n) {
  int i = (blockIdx.x * 256 + threadIdx.x) * 8;
  if (i >= n) return;
  float4 a = *(const float4*)&in[i];
  float4 b = *(const float4*)&in[i + 4];
  short8 o;
  o[0] = (short)f2bf(a.x); o[1] = (short)f2bf(a.y);
  o[2] = (short)f2bf(a.z); o[3] = (short)f2bf(a.w);
  o[4] = (short)f2bf(b.x); o[5] = (short)f2bf(b.y);
  o[6] = (short)f2bf(b.z); o[7] = (short)f2bf(b.w);
  *(short8*)&out[i] = o;
}

__global__ __launch_bounds__(256) void cvtT_kernel(
    const float* __restrict__ in, unsigned short* __restrict__ out, int K, int N) {
  __shared__ unsigned short tile[32][33];
  int n0 = blockIdx.x * 32, k0 = blockIdx.y * 32;
  int tx = threadIdx.x, ty = threadIdx.y;
#pragma unroll
  for (int i = 0; i < 32; i += 8)
    tile[ty + i][tx] = f2bf(in[(size_t)(k0 + ty + i) * N + n0 + tx]);
  __syncthreads();
#pragma unroll
  for (int i = 0; i < 32; i += 8)
    out[(size_t)(n0 + ty + i) * K + k0 + tx] = tile[tx][ty + i];
}

#define GEMM128_BODY(APTR, BPTR)                                                   \
  __shared__ __align__(16) unsigned short As[128][64];                             \
  __shared__ __align__(16) unsigned short Bs[128][64];                             \
  const int m0 = blockIdx.y * 128, n0 = blockIdx.x * 128;                          \
  const int t = threadIdx.x, lane = t & 63, wave = t >> 6;                         \
  const int quad = lane >> 4, l16 = lane & 15;                                     \
  const int wm = (wave >> 1) * 64, wn = (wave & 1) * 64;                           \
  const int lr = lane >> 3, lc = lane & 7, sc8 = (lc ^ lr) * 8;                    \
  const int sw = l16 & 7;                                                          \
  const int pA0 = (quad ^ sw) * 8, pA1 = ((4 + quad) ^ sw) * 8;                    \
  floatx4 acc[4][4];                                                               \
  _Pragma("unroll") for (int mi = 0; mi < 4; mi++)                                 \
      _Pragma("unroll") for (int ni = 0; ni < 4; ni++)                             \
          acc[mi][ni] = (floatx4){0.f, 0.f, 0.f, 0.f};                             \
  for (int k0 = 0; k0 < DIM; k0 += 64) {                                           \
    _Pragma("unroll") for (int i = 0; i < 4; i++) {                                \
      int rb = wave * 32 + i * 8;                                                  \
      async16(&APTR[(size_t)(m0 + rb + lr) * DIM + k0 + sc8], &As[rb][0]);         \
      async16(&BPTR[(size_t)(n0 + rb + lr) * DIM + k0 + sc8], &Bs[rb][0]);         \
    }                                                                              \
    __syncthreads();                                                               \
    short8 a0[4], a1[4];                                                           \
    _Pragma("unroll") for (int mi = 0; mi < 4; mi++) {                             \
      int row = wm + mi * 16 + l16;                                                \
      a0[mi] = *(const short8*)&As[row][pA0];                                      \
      a1[mi] = *(const short8*)&As[row][pA1];                                      \
    }                                                                              \
    _Pragma("unroll") for (int ni = 0; ni < 4; ni++) {                             \
      int row = wn + ni * 16 + l16;                                                \
      short8 b0 = *(const short8*)&Bs[row][pA0];                                   \
      short8 b1 = *(const short8*)&Bs[row][pA1];                                   \
      _Pragma("unroll") for (int mi = 0; mi < 4; mi++) {                           \
        acc[mi][ni] = __builtin_amdgcn_mfma_f32_16x16x32_bf16(a0[mi], b0, acc[mi][ni], 0, 0, 0); \
        acc[mi][ni] = __builtin_amdgcn_mfma_f32_16x16x32_bf16(a1[mi], b1, acc[mi][ni], 0, 0, 0); \
      }                                                                            \
    }                                                                              \
    __syncthreads();                                                               \
  }

__global__ __launch_bounds__(256) void gemm_qkv128(
    const unsigned short* __restrict__ Xb,
    const unsigned short* __restrict__ Wt,
    const float* __restrict__ bias,
    unsigned short* __restrict__ Qg,
    unsigned short* __restrict__ Kg,
    unsigned short* __restrict__ Vgt) {
  GEMM128_BODY(Xb, Wt)
  const int section = n0 >> 10;
  const int head = ((n0 + wn) >> 6) & 15;
#pragma unroll
  for (int mi = 0; mi < 4; mi++) {
    int mg = m0 + wm + mi * 16 + quad * 4;
    int bb = mg >> 11, sb = mg & 2047;
    size_t y = (size_t)bb * NHEAD + head;
    if (section == 2) {
#pragma unroll
      for (int ni = 0; ni < 4; ni++) {
        int hdi = ni * 16 + l16;
        float bv = bias[n0 + wn + hdi];
        ushort4v o;
#pragma unroll
        for (int r = 0; r < 4; r++) o[r] = f2bf(acc[mi][ni][r] + bv);
        *(ushort4v*)&Vgt[(y * HDIM + hdi) * S_LEN + sb] = o;
      }
    } else if (section == 0) {
#pragma unroll
      for (int ni = 0; ni < 4; ni++) {
        int hdi = ni * 16 + l16;
        float bv = bias[n0 + wn + hdi];
#pragma unroll
        for (int r = 0; r < 4; r++)
          Qg[(y * S_LEN + sb + r) * HDIM + hdi] = f2bf((acc[mi][ni][r] + bv) * Q_PRESCALE);
      }
    } else {
#pragma unroll
      for (int ni = 0; ni < 4; ni++) {
        int hdi = ni * 16 + l16;
        float bv = bias[n0 + wn + hdi];
#pragma unroll
        for (int r = 0; r < 4; r++)
          Kg[(y * S_LEN + sb + r) * HDIM + hdi] = f2bf(acc[mi][ni][r] + bv);
      }
    }
  }
}

__global__ __launch_bounds__(256) void gemm_out128(
    const unsigned short* __restrict__ A,
    const unsigned short* __restrict__ Wt,
    const float* __restrict__ bias,
    float* __restrict__ outp) {
  GEMM128_BODY(A, Wt)
#pragma unroll
  for (int ni = 0; ni < 4; ni++) {
    int n = n0 + wn + ni * 16 + l16;
    float bv = bias[n];
#pragma unroll
    for (int mi = 0; mi < 4; mi++) {
      int mg = m0 + wm + mi * 16 + quad * 4;
#pragma unroll
      for (int r = 0; r < 4; r++)
        outp[(size_t)(mg + r) * DIM + n] = acc[mi][ni][r] + bv;
    }
  }
}

__global__ __launch_bounds__(256) void attn_kernel(
    const unsigned short* __restrict__ Qg,
    const unsigned short* __restrict__ Kg,
    const unsigned short* __restrict__ Vgt,
    unsigned short* __restrict__ attnB) {
  __shared__ __align__(16) unsigned short Ks[2][64][64];
  __shared__ __align__(16) unsigned short Vs[2][64][64];
  __shared__ __align__(16) unsigned short Ones[16][64];
  __shared__ __align__(16) unsigned short Ps[4][16][72];

  const int y = blockIdx.x;
  const int b = y >> 4, h = y & 15;
  const int qt = 31 - blockIdx.y;
  const int q0 = qt * 64;
  const int nT = qt + 1;
  const int t = threadIdx.x;
  const int lane = t & 63, wave = t >> 6;
  const int quad = lane >> 4, l16 = lane & 15;
  const int lr = lane >> 3, lc = lane & 7;
  const int sc8 = (lc ^ lr) * 8;
  const int sw = l16 & 7;
  const int p0 = (quad ^ sw) * 8, p1 = ((4 + quad) ^ sw) * 8;

  const unsigned short* Qh = Qg + (size_t)y * S_LEN * HDIM;
  const unsigned short* Kh = Kg + (size_t)y * S_LEN * HDIM;
  const unsigned short* Vh = Vgt + (size_t)y * HDIM * S_LEN;

  if (t < 128) {
    int row = t >> 3, c = (t & 7) * 8;
    unsigned short vv = (row == 0) ? (unsigned short)0x3F80 : (unsigned short)0;
    short8 o;
#pragma unroll
    for (int j = 0; j < 8; j++) o[j] = (short)vv;
    *(short8*)&Ones[row][c] = o;
  }

  short8 aq0, aq1;
  {
    const unsigned short* qp = &Qh[(size_t)(q0 + wave * 16 + l16) * HDIM];
    aq0 = *(const short8*)&qp[quad * 8];
    aq1 = *(const short8*)&qp[32 + quad * 8];
  }

  floatx4 o_acc[5];
#pragma unroll
  for (int dt = 0; dt < 5; dt++) o_acc[dt] = (floatx4){0.f, 0.f, 0.f, 0.f};

  {
    int rb = wave * 16;
#pragma unroll
    for (int i = 0; i < 2; i++) {
      async16(&Kh[(size_t)(rb + i * 8 + lr) * HDIM + sc8], &Ks[0][rb + i * 8][0]);
      async16(&Vh[(size_t)(rb + i * 8 + lr) * S_LEN + sc8], &Vs[0][rb + i * 8][0]);
    }
  }

  for (int tt = 0; tt < nT; tt++) {
    const int j0 = tt * 64;
    const int buf = tt & 1;
    __syncthreads();
    if (tt + 1 < nT) {
      int j1 = j0 + 64, nb = 1 - buf;
      int rb = wave * 16;
#pragma unroll
      for (int i = 0; i < 2; i++) {
        async16(&Kh[(size_t)(j1 + rb + i * 8 + lr) * HDIM + sc8], &Ks[nb][rb + i * 8][0]);
        async16(&Vh[(size_t)(rb + i * 8 + lr) * S_LEN + j1 + sc8], &Vs[nb][rb + i * 8][0]);
      }
    }

    floatx4 sc[4];
#pragma unroll
    for (int nt = 0; nt < 4; nt++) {
      short8 kb0 = *(const short8*)&Ks[buf][nt * 16 + l16][p0];
      short8 kb1 = *(const short8*)&Ks[buf][nt * 16 + l16][p1];
      sc[nt] = (floatx4){0.f, 0.f, 0.f, 0.f};
      sc[nt] = __builtin_amdgcn_mfma_f32_16x16x32_bf16(aq0, kb0, sc[nt], 0, 0, 0);
      sc[nt] = __builtin_amdgcn_mfma_f32_16x16x32_bf16(aq1, kb1, sc[nt], 0, 0, 0);
    }

    if (j0 == q0) {
#pragma unroll
      for (int nt = 0; nt < 4; nt++) {
        int keyl = nt * 16 + l16;
#pragma unroll
        for (int r = 0; r < 4; r++) {
          int ql = wave * 16 + quad * 4 + r;
          float p = exp2f(sc[nt][r]);
          p = (keyl <= ql) ? p : 0.f;
          Ps[wave][quad * 4 + r][nt * 16 + l16] = f2bf(p);
        }
      }
    } else {
#pragma unroll
      for (int nt = 0; nt < 4; nt++)
#pragma unroll
        for (int r = 0; r < 4; r++)
          Ps[wave][quad * 4 + r][nt * 16 + l16] = f2bf(exp2f(sc[nt][r]));
    }
    short8 ap0 = *(const short8*)&Ps[wave][l16][quad * 8];
    short8 ap1 = *(const short8*)&Ps[wave][l16][32 + quad * 8];

#pragma unroll
    for (int dt = 0; dt < 5; dt++) {
      short8 vb0 = (dt < 4) ? *(const short8*)&Vs[buf][dt * 16 + l16][p0]
                            : *(const short8*)&Ones[l16][p0];
      short8 vb1 = (dt < 4) ? *(const short8*)&Vs[buf][dt * 16 + l16][p1]
                            : *(const short8*)&Ones[l16][p1];
      o_acc[dt] = __builtin_amdgcn_mfma_f32_16x16x32_bf16(ap0, vb0, o_acc[dt], 0, 0, 0);
      o_acc[dt] = __builtin_amdgcn_mfma_f32_16x16x32_bf16(ap1, vb1, o_acc[dt], 0, 0, 0);
    }
  }

  float linv[4];
#pragma unroll
  for (int r = 0; r < 4; r++)
    linv[r] = 1.0f / __shfl(o_acc[4][r], quad << 4);
#pragma unroll
  for (int dt = 0; dt < 4; dt++)
#pragma unroll
    for (int r = 0; r < 4; r++) {
      int qg = q0 + wave * 16 + quad * 4 + r;
      attnB[(size_t)(b * S_LEN + qg) * DIM + h * HDIM + dt * 16 + l16] =
          f2bf(o_acc[dt][r] * linv[r]);
    }
}

extern "C" void kernel_launch(void* const* d_in, const int* in_sizes, int n_in,
                              void* d_out, int out_size, void* d_ws, size_t ws_size,
                              hipStream_t stream) {
  const float* X    = (const float*)d_in[0];
  const float* Wqkv = (const float*)d_in[1];
  const float* bqkv = (const float*)d_in[2];
  const float* Wout = (const float*)d_in[3];
  const float* bout = (const float*)d_in[4];
  float* outp = (float*)d_out;

  unsigned short* Wqkvt = (unsigned short*)d_ws;
  unsigned short* Woutt = Wqkvt + (size_t)3145728;
  unsigned short* attnB = Woutt + (size_t)1048576;
  unsigned short* Qg    = attnB + (size_t)4194304;
  unsigned short* Kg    = Qg + (size_t)4194304;
  unsigned short* Vgt   = Kg + (size_t)4194304;
  unsigned short* Xb    = Vgt + (size_t)4194304;

  // --- preferred: one cooperative mega-kernel (no inter-dispatch gaps) ---
  void* args[] = {(void*)&X, (void*)&Wqkv, (void*)&bqkv, (void*)&Wout, (void*)&bout,
                  (void*)&outp, (void*)&Wqkvt, (void*)&Woutt, (void*)&attnB,
                  (void*)&Qg, (void*)&Kg, (void*)&Vgt, (void*)&Xb};
  hipError_t err = hipLaunchCooperativeKernel((const void*)fused_kernel,
                                              dim3(256), dim3(512), args, 0, stream);
  if (err == hipSuccess) return;
  (void)hipGetLastError();   // clear error state

  // --- fallback: proven round-10 multi-kernel path ---
  cvtT_kernel<<<dim3(96, 32), dim3(32, 8), 0, stream>>>(Wqkv, Wqkvt, 1024, 3072);
  cvtT_kernel<<<dim3(32, 32), dim3(32, 8), 0, stream>>>(Wout, Woutt, 1024, 1024);
  cvt_kernel<<<4194304 / (256 * 8), 256, 0, stream>>>(X, Xb, 4194304);
  gemm_qkv128<<<dim3(24, 32), 256, 0, stream>>>(Xb, Wqkvt, bqkv, Qg, Kg, Vgt);
  attn_kernel<<<dim3(32, 32), 256, 0, stream>>>(Qg, Kg, Vgt, attnB);
  gemm_out128<<<dim3(8, 32), 256, 0, stream>>>(attnB, Woutt, bout, outp);
}

// Round 12
// 191.435 us; speedup vs baseline: 2.4476x; 2.4476x over previous
//
#include <hip/hip_runtime.h>

// Problem: B=2, S=2048, D=1024, H=16, hd=64. fp32 in/out; internal bf16 MFMA.
#define S_LEN 2048
#define DIM   1024
#define NHEAD 16
#define HDIM  64
#define Q_PRESCALE 0.045084220027780106f   // log2(e)/sqrt(D): exp2 softmax

typedef __attribute__((ext_vector_type(8))) short  short8;   // 8 bf16
typedef __attribute__((ext_vector_type(4))) float  floatx4;  // MFMA C/D
typedef __attribute__((ext_vector_type(4))) unsigned short ushort4v;

__device__ inline unsigned short f2bf(float f) {
  unsigned v = __builtin_bit_cast(unsigned, f);
  v += 0x7FFFu + ((v >> 16) & 1u);   // RTNE
  return (unsigned short)(v >> 16);
}

// async global->LDS, 16B/lane; LDS dest = wave-uniform base + lane*16.
__device__ inline void async16(const unsigned short* g, unsigned short* l) {
  __builtin_amdgcn_global_load_lds(
      (const __attribute__((address_space(1))) unsigned int*)g,
      (__attribute__((address_space(3))) unsigned int*)l, 16, 0, 0);
}

// ---- prep: W transposes (+cvt) and optional X cvt, ONE launch ----
// blocks [0,3072): Wqkv 32x32 transpose tiles; [3072,4096): Wout tiles;
// [4096,6144): X fp32->bf16 (2048 elems/block). Launch 4096 blocks if no Xb.
__global__ __launch_bounds__(256) void prep_kernel(
    const float* __restrict__ X, const float* __restrict__ Wqkv,
    const float* __restrict__ Wout, unsigned short* __restrict__ Xb,
    unsigned short* __restrict__ Wqkvt, unsigned short* __restrict__ Woutt) {
  const int j = blockIdx.x, t = threadIdx.x;
  if (j >= 4096) {
    int i = ((j - 4096) * 256 + t) * 8;
    float4 a = *(const float4*)&X[i];
    float4 b = *(const float4*)&X[i + 4];
    short8 o;
    o[0] = (short)f2bf(a.x); o[1] = (short)f2bf(a.y);
    o[2] = (short)f2bf(a.z); o[3] = (short)f2bf(a.w);
    o[4] = (short)f2bf(b.x); o[5] = (short)f2bf(b.y);
    o[6] = (short)f2bf(b.z); o[7] = (short)f2bf(b.w);
    *(short8*)&Xb[i] = o;
    return;
  }
  __shared__ unsigned short tile[32][33];
  const float* in; unsigned short* out; int N, tn, tk;
  if (j < 3072) { in = Wqkv; out = Wqkvt; N = 3072; tn = j % 96; tk = j / 96; }
  else { int u = j - 3072; in = Wout; out = Woutt; N = 1024; tn = u & 31; tk = u >> 5; }
  const int n0 = tn * 32, k0 = tk * 32;
  const int tx = t & 31, ty = t >> 5;   // 32 x 8
#pragma unroll
  for (int i = 0; i < 32; i += 8)
    tile[ty + i][tx] = f2bf(in[(size_t)(k0 + ty + i) * N + n0 + tx]);
  __syncthreads();
#pragma unroll
  for (int i = 0; i < 32; i += 8)
    out[(size_t)(n0 + ty + i) * 1024 + k0 + tx] = tile[tx][ty + i];
}

// ================= 128x128-tile MFMA GEMM core (m97 structure) =================
#define GEMM128_BODY(APTR, BPTR)                                                   \
  __shared__ __align__(16) unsigned short As[128][64];                             \
  __shared__ __align__(16) unsigned short Bs[128][64];                             \
  const int m0 = blockIdx.y * 128, n0 = blockIdx.x * 128;                          \
  const int t = threadIdx.x, lane = t & 63, wave = t >> 6;                         \
  const int quad = lane >> 4, l16 = lane & 15;                                     \
  const int wm = (wave >> 1) * 64, wn = (wave & 1) * 64;                           \
  const int lr = lane >> 3, lc = lane & 7, sc8 = (lc ^ lr) * 8;                    \
  const int sw = l16 & 7;                                                          \
  const int pA0 = (quad ^ sw) * 8, pA1 = ((4 + quad) ^ sw) * 8;                    \
  floatx4 acc[4][4];                                                               \
  _Pragma("unroll") for (int mi = 0; mi < 4; mi++)                                 \
      _Pragma("unroll") for (int ni = 0; ni < 4; ni++)                             \
          acc[mi][ni] = (floatx4){0.f, 0.f, 0.f, 0.f};                             \
  for (int k0 = 0; k0 < DIM; k0 += 64) {                                           \
    _Pragma("unroll") for (int i = 0; i < 4; i++) {                                \
      int rb = wave * 32 + i * 8;                                                  \
      async16(&APTR[(size_t)(m0 + rb + lr) * DIM + k0 + sc8], &As[rb][0]);         \
      async16(&BPTR[(size_t)(n0 + rb + lr) * DIM + k0 + sc8], &Bs[rb][0]);         \
    }                                                                              \
    __syncthreads();                                                               \
    short8 a0[4], a1[4];                                                           \
    _Pragma("unroll") for (int mi = 0; mi < 4; mi++) {                             \
      int row = wm + mi * 16 + l16;                                                \
      a0[mi] = *(const short8*)&As[row][pA0];                                      \
      a1[mi] = *(const short8*)&As[row][pA1];                                      \
    }                                                                              \
    _Pragma("unroll") for (int ni = 0; ni < 4; ni++) {                             \
      int row = wn + ni * 16 + l16;                                                \
      short8 b0 = *(const short8*)&Bs[row][pA0];                                   \
      short8 b1 = *(const short8*)&Bs[row][pA1];                                   \
      _Pragma("unroll") for (int mi = 0; mi < 4; mi++) {                           \
        acc[mi][ni] = __builtin_amdgcn_mfma_f32_16x16x32_bf16(a0[mi], b0, acc[mi][ni], 0, 0, 0); \
        acc[mi][ni] = __builtin_amdgcn_mfma_f32_16x16x32_bf16(a1[mi], b1, acc[mi][ni], 0, 0, 0); \
      }                                                                            \
    }                                                                              \
    __syncthreads();                                                               \
  }

// ---- GEMM1: qkv = Xb @ Wqkvt^T + b, scatter Q(prescaled)/K/Vt ----
__global__ __launch_bounds__(256) void gemm_qkv128(
    const unsigned short* __restrict__ Xb,
    const unsigned short* __restrict__ Wt,
    const float* __restrict__ bias,
    unsigned short* __restrict__ Qg,
    unsigned short* __restrict__ Kg,
    unsigned short* __restrict__ Vgt) {
  GEMM128_BODY(Xb, Wt)
  const int section = n0 >> 10;
  const int head = ((n0 + wn) >> 6) & 15;
#pragma unroll
  for (int mi = 0; mi < 4; mi++) {
    int mg = m0 + wm + mi * 16 + quad * 4;
    int bb = mg >> 11, sb = mg & 2047;
    size_t y = (size_t)bb * NHEAD + head;
    if (section == 2) {
#pragma unroll
      for (int ni = 0; ni < 4; ni++) {
        int hdi = ni * 16 + l16;
        float bv = bias[n0 + wn + hdi];
        ushort4v o;
#pragma unroll
        for (int r = 0; r < 4; r++) o[r] = f2bf(acc[mi][ni][r] + bv);
        *(ushort4v*)&Vgt[(y * HDIM + hdi) * S_LEN + sb] = o;
      }
    } else if (section == 0) {
#pragma unroll
      for (int ni = 0; ni < 4; ni++) {
        int hdi = ni * 16 + l16;
        float bv = bias[n0 + wn + hdi];
#pragma unroll
        for (int r = 0; r < 4; r++)
          Qg[(y * S_LEN + sb + r) * HDIM + hdi] = f2bf((acc[mi][ni][r] + bv) * Q_PRESCALE);
      }
    } else {
#pragma unroll
      for (int ni = 0; ni < 4; ni++) {
        int hdi = ni * 16 + l16;
        float bv = bias[n0 + wn + hdi];
#pragma unroll
        for (int r = 0; r < 4; r++)
          Kg[(y * S_LEN + sb + r) * HDIM + hdi] = f2bf(acc[mi][ni][r] + bv);
      }
    }
  }
}

// ---- GEMM2: out = attnB @ Woutt^T + b (fp32 out) ----
__global__ __launch_bounds__(256) void gemm_out128(
    const unsigned short* __restrict__ A,
    const unsigned short* __restrict__ Wt,
    const float* __restrict__ bias,
    float* __restrict__ outp) {
  GEMM128_BODY(A, Wt)
#pragma unroll
  for (int ni = 0; ni < 4; ni++) {
    int n = n0 + wn + ni * 16 + l16;
    float bv = bias[n];
#pragma unroll
    for (int mi = 0; mi < 4; mi++) {
      int mg = m0 + wm + mi * 16 + quad * 4;
#pragma unroll
      for (int r = 0; r < 4; r++)
        outp[(size_t)(mg + r) * DIM + n] = acc[mi][ni][r] + bv;
    }
  }
}

// ---- fallback GEMM1 (64-tile, inline X convert) for ws_size < 48 MiB ----
__global__ __launch_bounds__(256) void gemm_qkv_kernel(
    const float* __restrict__ X,
    const unsigned short* __restrict__ Wt,
    const float* __restrict__ bias,
    unsigned short* __restrict__ Qg,
    unsigned short* __restrict__ Kg,
    unsigned short* __restrict__ Vgt,
    int g0, int G) {
  __shared__ __align__(16) unsigned short As[64][72];
  __shared__ __align__(16) unsigned short Bs[64][72];
  const int tn = blockIdx.x;
  const int section = tn / G, within = tn % G;
  const int n0 = section * 1024 + (g0 + within) * 64;
  const int m0 = blockIdx.y * 64;
  const int t = threadIdx.x, lane = t & 63, wave = t >> 6;
  const int quad = lane >> 4, l16 = lane & 15;

  floatx4 acc[4];
#pragma unroll
  for (int i = 0; i < 4; i++) acc[i] = (floatx4){0.f, 0.f, 0.f, 0.f};

  for (int k0 = 0; k0 < DIM; k0 += 64) {
#pragma unroll
    for (int i = 0; i < 2; i++) {
      int v = t + i * 256;
      int row = v >> 3, cc = (v & 7) * 8;
      float4 f0 = *(const float4*)&X[(size_t)(m0 + row) * DIM + k0 + cc];
      float4 f1 = *(const float4*)&X[(size_t)(m0 + row) * DIM + k0 + cc + 4];
      short8 o;
      o[0] = (short)f2bf(f0.x); o[1] = (short)f2bf(f0.y);
      o[2] = (short)f2bf(f0.z); o[3] = (short)f2bf(f0.w);
      o[4] = (short)f2bf(f1.x); o[5] = (short)f2bf(f1.y);
      o[6] = (short)f2bf(f1.z); o[7] = (short)f2bf(f1.w);
      *(short8*)&As[row][cc] = o;
      *(short8*)&Bs[row][cc] = *(const short8*)&Wt[(size_t)(n0 + row) * DIM + k0 + cc];
    }
    __syncthreads();
    short8 a0 = *(const short8*)&As[wave * 16 + l16][quad * 8];
    short8 a1 = *(const short8*)&As[wave * 16 + l16][32 + quad * 8];
#pragma unroll
    for (int nt = 0; nt < 4; nt++) {
      short8 b0 = *(const short8*)&Bs[nt * 16 + l16][quad * 8];
      short8 b1 = *(const short8*)&Bs[nt * 16 + l16][32 + quad * 8];
      acc[nt] = __builtin_amdgcn_mfma_f32_16x16x32_bf16(a0, b0, acc[nt], 0, 0, 0);
      acc[nt] = __builtin_amdgcn_mfma_f32_16x16x32_bf16(a1, b1, acc[nt], 0, 0, 0);
    }
    __syncthreads();
  }

  const int mbase = m0 + wave * 16 + quad * 4;
  const int b = mbase >> 11, sbase = mbase & 2047;
  const int y = b * G + within;
  if (section == 2) {
#pragma unroll
    for (int nt = 0; nt < 4; nt++) {
      int hdi = nt * 16 + l16;
      float bv = bias[n0 + hdi];
      ushort4v o;
#pragma unroll
      for (int r = 0; r < 4; r++) o[r] = f2bf(acc[nt][r] + bv);
      *(ushort4v*)&Vgt[((size_t)y * HDIM + hdi) * S_LEN + sbase] = o;
    }
  } else if (section == 0) {
#pragma unroll
    for (int nt = 0; nt < 4; nt++) {
      int hdi = nt * 16 + l16;
      float bv = bias[n0 + hdi];
#pragma unroll
      for (int r = 0; r < 4; r++)
        Qg[((size_t)y * S_LEN + sbase + r) * HDIM + hdi] =
            f2bf((acc[nt][r] + bv) * Q_PRESCALE);
    }
  } else {
#pragma unroll
    for (int nt = 0; nt < 4; nt++) {
      int hdi = nt * 16 + l16;
      float bv = bias[n0 + hdi];
#pragma unroll
      for (int r = 0; r < 4; r++)
        Kg[((size_t)y * S_LEN + sbase + r) * HDIM + hdi] = f2bf(acc[nt][r] + bv);
    }
  }
}

// ---- attention v4 (round-10, proven): 64-row q-tile, 1024 blocks heavy-first ----
__global__ __launch_bounds__(256) void attn_kernel(
    const unsigned short* __restrict__ Qg,
    const unsigned short* __restrict__ Kg,
    const unsigned short* __restrict__ Vgt,
    unsigned short* __restrict__ attnB) {
  __shared__ __align__(16) unsigned short Ks[2][64][64];   // [buf][key][hd], XOR-swizzled
  __shared__ __align__(16) unsigned short Vs[2][64][64];   // [buf][hd][key], XOR-swizzled
  __shared__ __align__(16) unsigned short Ones[16][64];    // row0=1.0 (swizzle-invariant)
  __shared__ __align__(16) unsigned short Ps[4][16][72];   // per-wave P [qrow][key]

  const int y = blockIdx.x;                // 0..31
  const int b = y >> 4, h = y & 15;
  const int qt = 31 - blockIdx.y;          // heavy-first
  const int q0 = qt * 64;
  const int nT = qt + 1;
  const int t = threadIdx.x;
  const int lane = t & 63, wave = t >> 6;
  const int quad = lane >> 4, l16 = lane & 15;
  const int lr = lane >> 3, lc = lane & 7;
  const int sc8 = (lc ^ lr) * 8;
  const int sw = l16 & 7;
  const int p0 = (quad ^ sw) * 8, p1 = ((4 + quad) ^ sw) * 8;

  const unsigned short* Qh = Qg + (size_t)y * S_LEN * HDIM;
  const unsigned short* Kh = Kg + (size_t)y * S_LEN * HDIM;
  const unsigned short* Vh = Vgt + (size_t)y * HDIM * S_LEN;

  if (t < 128) {
    int row = t >> 3, c = (t & 7) * 8;
    unsigned short vv = (row == 0) ? (unsigned short)0x3F80 : (unsigned short)0;
    short8 o;
#pragma unroll
    for (int j = 0; j < 8; j++) o[j] = (short)vv;
    *(short8*)&Ones[row][c] = o;
  }

  short8 aq0, aq1;
  {
    const unsigned short* qp = &Qh[(size_t)(q0 + wave * 16 + l16) * HDIM];
    aq0 = *(const short8*)&qp[quad * 8];
    aq1 = *(const short8*)&qp[32 + quad * 8];
  }

  floatx4 o_acc[5];
#pragma unroll
  for (int dt = 0; dt < 5; dt++) o_acc[dt] = (floatx4){0.f, 0.f, 0.f, 0.f};

  {
    int rb = wave * 16;
#pragma unroll
    for (int i = 0; i < 2; i++) {
      async16(&Kh[(size_t)(rb + i * 8 + lr) * HDIM + sc8], &Ks[0][rb + i * 8][0]);
      async16(&Vh[(size_t)(rb + i * 8 + lr) * S_LEN + sc8], &Vs[0][rb + i * 8][0]);
    }
  }

  for (int tt = 0; tt < nT; tt++) {
    const int j0 = tt * 64;
    const int buf = tt & 1;
    __syncthreads();
    if (tt + 1 < nT) {
      int j1 = j0 + 64, nb = 1 - buf;
      int rb = wave * 16;
#pragma unroll
      for (int i = 0; i < 2; i++) {
        async16(&Kh[(size_t)(j1 + rb + i * 8 + lr) * HDIM + sc8], &Ks[nb][rb + i * 8][0]);
        async16(&Vh[(size_t)(rb + i * 8 + lr) * S_LEN + j1 + sc8], &Vs[nb][rb + i * 8][0]);
      }
    }

    floatx4 sc[4];
#pragma unroll
    for (int nt = 0; nt < 4; nt++) {
      short8 kb0 = *(const short8*)&Ks[buf][nt * 16 + l16][p0];
      short8 kb1 = *(const short8*)&Ks[buf][nt * 16 + l16][p1];
      sc[nt] = (floatx4){0.f, 0.f, 0.f, 0.f};
      sc[nt] = __builtin_amdgcn_mfma_f32_16x16x32_bf16(aq0, kb0, sc[nt], 0, 0, 0);
      sc[nt] = __builtin_amdgcn_mfma_f32_16x16x32_bf16(aq1, kb1, sc[nt], 0, 0, 0);
    }

    if (j0 == q0) {
#pragma unroll
      for (int nt = 0; nt < 4; nt++) {
        int keyl = nt * 16 + l16;
#pragma unroll
        for (int r = 0; r < 4; r++) {
          int ql = wave * 16 + quad * 4 + r;
          float p = exp2f(sc[nt][r]);
          p = (keyl <= ql) ? p : 0.f;
          Ps[wave][quad * 4 + r][nt * 16 + l16] = f2bf(p);
        }
      }
    } else {
#pragma unroll
      for (int nt = 0; nt < 4; nt++)
#pragma unroll
        for (int r = 0; r < 4; r++)
          Ps[wave][quad * 4 + r][nt * 16 + l16] = f2bf(exp2f(sc[nt][r]));
    }
    short8 ap0 = *(const short8*)&Ps[wave][l16][quad * 8];
    short8 ap1 = *(const short8*)&Ps[wave][l16][32 + quad * 8];

#pragma unroll
    for (int dt = 0; dt < 5; dt++) {
      short8 vb0 = (dt < 4) ? *(const short8*)&Vs[buf][dt * 16 + l16][p0]
                            : *(const short8*)&Ones[l16][p0];
      short8 vb1 = (dt < 4) ? *(const short8*)&Vs[buf][dt * 16 + l16][p1]
                            : *(const short8*)&Ones[l16][p1];
      o_acc[dt] = __builtin_amdgcn_mfma_f32_16x16x32_bf16(ap0, vb0, o_acc[dt], 0, 0, 0);
      o_acc[dt] = __builtin_amdgcn_mfma_f32_16x16x32_bf16(ap1, vb1, o_acc[dt], 0, 0, 0);
    }
  }

  float linv[4];
#pragma unroll
  for (int r = 0; r < 4; r++)
    linv[r] = 1.0f / __shfl(o_acc[4][r], quad << 4);
#pragma unroll
  for (int dt = 0; dt < 4; dt++)
#pragma unroll
    for (int r = 0; r < 4; r++) {
      int qg = q0 + wave * 16 + quad * 4 + r;
      attnB[(size_t)(b * S_LEN + qg) * DIM + h * HDIM + dt * 16 + l16] =
          f2bf(o_acc[dt][r] * linv[r]);
    }
}

extern "C" void kernel_launch(void* const* d_in, const int* in_sizes, int n_in,
                              void* d_out, int out_size, void* d_ws, size_t ws_size,
                              hipStream_t stream) {
  const float* X    = (const float*)d_in[0];
  const float* Wqkv = (const float*)d_in[1];
  const float* bqkv = (const float*)d_in[2];
  const float* Wout = (const float*)d_in[3];
  const float* bout = (const float*)d_in[4];
  float* outp = (float*)d_out;

  unsigned short* Wqkvt = (unsigned short*)d_ws;
  unsigned short* Woutt = Wqkvt + (size_t)3145728;
  unsigned short* attnB = Woutt + (size_t)1048576;
  unsigned short* Qg    = attnB + (size_t)4194304;
  unsigned short* Kg    = Qg + (size_t)4194304;
  unsigned short* Vgt   = Kg + (size_t)4194304;
  unsigned short* Xb    = Vgt + (size_t)4194304;

  const bool bigWs = ws_size >= (size_t)48 * 1024 * 1024;

  if (bigWs) {
    // one prep launch: W transposes (blocks 0..4095) + X cvt (blocks 4096..6143)
    prep_kernel<<<6144, 256, 0, stream>>>(X, Wqkv, Wout, Xb, Wqkvt, Woutt);
    gemm_qkv128<<<dim3(24, 32), 256, 0, stream>>>(Xb, Wqkvt, bqkv, Qg, Kg, Vgt);
  } else {
    // transposes only (no Xb room); 64-tile gemm converts X inline
    prep_kernel<<<4096, 256, 0, stream>>>(X, Wqkv, Wout, nullptr, Wqkvt, Woutt);
    gemm_qkv_kernel<<<dim3(48, 64), 256, 0, stream>>>(
        X, Wqkvt, bqkv, Qg, Kg, Vgt, 0, 16);
  }
  attn_kernel<<<dim3(32, 32), 256, 0, stream>>>(Qg, Kg, Vgt, attnB);
  gemm_out128<<<dim3(8, 32), 256, 0, stream>>>(attnB, Woutt, bout, outp);
}